// Round 18
// baseline (660.406 us; speedup 1.0000x reference)
//
#include <hip/hip_runtime.h>
#include <math.h>

// Problem constants (fixed by setup_inputs: B=8, UPD=32, PPD=64)
#define H      256
#define NH     8
#define DH     32
#define FFDIM  1024
#define L1     128      // DEPTH*UNIT_LEN
#define B1     512      // B*PPD
#define L2     512      // UPD*UNIT_LEN
#define B2     8        // nb
#define N1     (L1*B1)  // 65536
#define N2     (L2*B2)  // 4096
#define RT1    (N1/128) // 512 row tiles enc1
#define RT2    (N2/128) // 32 row tiles enc2
#define QSCL   0.25506602273492887f   // (1/sqrt(32)) * log2(e)

typedef unsigned short u16;
typedef unsigned short ushort4_t __attribute__((ext_vector_type(4)));
typedef unsigned short ushort8_t __attribute__((ext_vector_type(8)));
typedef short          short8_t  __attribute__((ext_vector_type(8)));
typedef float          f32x4     __attribute__((ext_vector_type(4)));

__device__ __forceinline__ float bf2f(u16 u) {
    union { unsigned int i; float f; } v; v.i = ((unsigned int)u) << 16; return v.f;
}
__device__ __forceinline__ u16 f2bf(float f) {
    union { float f; unsigned int i; } v; v.f = f;
    unsigned int x = v.i;
    return (u16)((x + 0x7fffu + ((x >> 16) & 1u)) >> 16);   // RNE
}
__device__ __forceinline__ unsigned cvt_pk_bf16(float lo, float hi) {
    unsigned r;
    asm("v_cvt_pk_bf16_f32 %0, %1, %2" : "=v"(r) : "v"(lo), "v"(hi));
    return r;                                     // lo in [15:0], hi in [31:16], RNE
}

// ---------------- merged f32 -> bf16 weight preconvert (1 dispatch) -------
__global__ __launch_bounds__(256) void k_f2bf8(
    const float* __restrict__ s0, const float* __restrict__ s1,
    const float* __restrict__ s2, const float* __restrict__ s3,
    const float* __restrict__ s4, const float* __restrict__ s5,
    const float* __restrict__ s6, const float* __restrict__ s7,
    u16* __restrict__ out)
{
    const int cums[9] = {0, 393216, 524288, 1048576, 1572864,
                         1966080, 2097152, 2621440, 3145728};
    const float* srcs[8] = {s0, s1, s2, s3, s4, s5, s6, s7};
    const int gbase = blockIdx.x * 1024;          // block-uniform segment
    int seg = 0;
    #pragma unroll
    for (int i = 1; i < 8; ++i) if (gbase >= cums[i]) seg = i;
    const int idx = gbase + threadIdx.x * 4;
    const int off = idx - cums[seg];
    const float fs = ((seg == 0 || seg == 4) && (off % 196608) < 65536)
                   ? QSCL : 1.0f;
    const float4 v = *(const float4*)(srcs[seg] + off);
    ushort4_t o;
    o.x = f2bf(v.x * fs); o.y = f2bf(v.y * fs);
    o.z = f2bf(v.z * fs); o.w = f2bf(v.w * fs);
    *(ushort4_t*)(out + idx) = o;
}

// ---------------- scaled qkv bias copy (Q cols x QSCL), f32 ---------------
__global__ __launch_bounds__(256) void k_scaleb(
    const float* __restrict__ b1, const float* __restrict__ b2,
    float* __restrict__ out)
{
    const int i = blockIdx.x * 256 + threadIdx.x;  // 0..3071
    const float* src = (i < 1536) ? b1 : b2;
    const int j = (i < 1536) ? i : i - 1536;
    float v = src[j];
    if ((j % 768) < 256) v *= QSCL;
    out[i] = v;
}

// ---------------- merged gather + embedding + PE (both encoders) ----------
__global__ __launch_bounds__(256) void k_gather(
    const int* __restrict__ units, const int* __restrict__ paths,
    const float* __restrict__ emb,
    u16* __restrict__ x1, u16* __restrict__ x2,
    int* __restrict__ tokb1, int* __restrict__ tokb2)
{
    const int wave = threadIdx.x >> 6, lane = threadIdx.x & 63;
    const int t = blockIdx.x * 4 + wave;
    int tokid, l;
    u16* xp; int* tokp;
    if (t < N1) {                       // enc1: ctx gather
        l = t / B1; const int b = t - l * B1;
        const int d = l >> 4, u = l & 15;
        const int col = (b >> 6) * 32 + paths[d * 512 + b];
        tokid = units[u * 256 + col];
        xp = x1 + (size_t)t * H; tokp = tokb1 + t;
    } else {                            // enc2: order gather
        const int t2 = t - N1;
        l = t2 / B2; const int b = t2 - l * B2;
        const int w = l >> 4, u = l & 15;
        tokid = units[u * 256 + b * 32 + w];
        xp = x2 + (size_t)t2 * H; tokp = tokb2 + t2;
    }
    if (lane == 0) *tokp = tokid;
    const int c = lane * 4;
    const float4 e = *(const float4*)(emb + (size_t)tokid * H + c);
    const float i0 = (float)(c >> 1);
    const float a0 = (float)l * expf(-0.07195578415606394f * i0);
    const float a1 = (float)l * expf(-0.07195578415606394f * (i0 + 1.0f));
    ushort4_t o;
    o.x = f2bf(e.x + sinf(a0));
    o.y = f2bf(e.y + cosf(a0));
    o.z = f2bf(e.z + sinf(a1));
    o.w = f2bf(e.w + cosf(a1));
    *(ushort4_t*)(xp + c) = o;
}

// ---------------- MFMA GEMM 128x128 (qkv, out-proj), merged encoders ------
// Single-pass epilogue: full 128x128 tile staged at stride 136, 1 barrier.
#define BUF_U16 8192      // one buffer: X[128][32] + W[128][32] = 16 KB
__global__ __launch_bounds__(256) void k_gemm_mfma(
    const u16* __restrict__ X1, const u16* __restrict__ X2,
    const u16* __restrict__ W1, const u16* __restrict__ W2,
    const float* __restrict__ b1, const float* __restrict__ b2,
    u16* __restrict__ Y1, u16* __restrict__ Y2,
    int K, int M, int relu)
{
    __shared__ __align__(16) u16 smem[17408];   // K-loop uses [0,16384)
    const int t = threadIdx.x;
    const int mtiles = M >> 7;
    const int nwg = gridDim.x;
    const int bid = blockIdx.x;
    const int wg = (bid & 7) * (nwg >> 3) + (bid >> 3);   // XCD-chunked
    const int rt = wg / mtiles;
    const int bn = (wg % mtiles) * 128;
    const u16* X; const u16* W; const float* bias; u16* Y; int bm;
    if (rt < RT1) { X = X1; W = W1; bias = b1; Y = Y1; bm = rt * 128; }
    else          { X = X2; W = W2; bias = b2; Y = Y2; bm = (rt - RT1) * 128; }
    const int wave = t >> 6, lane = t & 63;
    const int wr = (wave >> 1) * 64, wc = (wave & 1) * 64;
    const int lrow = lane & 15;
    const int lg   = lane >> 4;

    const u16* gx[2]; const u16* gw[2];
    int ldsxo[2], ldswo[2];
    #pragma unroll
    for (int i = 0; i < 2; ++i) {
        const int c = wave * 2 + i;
        const int r = c * 16 + (lane >> 2);
        const int s = (lane & 3) ^ ((r >> 1) & 3);
        gx[i] = X + (size_t)(bm + r) * K + s * 8;
        gw[i] = W + (size_t)(bn + r) * K + s * 8;
        ldsxo[i] = c * 512;
        ldswo[i] = 4096 + c * 512;
    }
    int aoff[4], boff[4];
    #pragma unroll
    for (int m = 0; m < 4; ++m) {
        const int R = wr + m * 16 + lrow;
        aoff[m] = R * 32 + ((lg ^ ((R >> 1) & 3)) * 8);
    }
    #pragma unroll
    for (int n = 0; n < 4; ++n) {
        const int R = wc + n * 16 + lrow;
        boff[n] = 4096 + R * 32 + ((lg ^ ((R >> 1) & 3)) * 8);
    }

    f32x4 acc[4][4] = {};
    const int nt = K >> 5;

    #pragma unroll
    for (int i = 0; i < 2; ++i) {
        __builtin_amdgcn_global_load_lds(gx[i], &smem[ldsxo[i]], 16, 0, 0);
        __builtin_amdgcn_global_load_lds(gw[i], &smem[ldswo[i]], 16, 0, 0);
        gx[i] += 32; gw[i] += 32;
    }
    __syncthreads();

    int cur = 0;
    for (int ts = 0; ts < nt; ++ts) {
        if (ts + 1 < nt) {
            const int nb = (cur ^ 1) * BUF_U16;
            #pragma unroll
            for (int i = 0; i < 2; ++i) {
                __builtin_amdgcn_global_load_lds(gx[i], &smem[nb + ldsxo[i]], 16, 0, 0);
                __builtin_amdgcn_global_load_lds(gw[i], &smem[nb + ldswo[i]], 16, 0, 0);
                gx[i] += 32; gw[i] += 32;
            }
        }
        const int cb = cur * BUF_U16;
        short8_t a[4], b[4];
        #pragma unroll
        for (int m = 0; m < 4; ++m) a[m] = *(const short8_t*)&smem[cb + aoff[m]];
        #pragma unroll
        for (int n = 0; n < 4; ++n) b[n] = *(const short8_t*)&smem[cb + boff[n]];
        #pragma unroll
        for (int m = 0; m < 4; ++m)
            #pragma unroll
            for (int n = 0; n < 4; ++n)
                acc[m][n] = __builtin_amdgcn_mfma_f32_16x16x32_bf16(
                    a[m], b[n], acc[m][n], 0, 0, 0);
        __syncthreads();
        cur ^= 1;
    }

    float bv[4];
    #pragma unroll
    for (int n = 0; n < 4; ++n) bv[n] = bias[bn + wc + n * 16 + lrow];
    const int r0 = (lane >> 4) * 4;

    #pragma unroll
    for (int n = 0; n < 4; ++n) {
        const int lc = wc + n * 16 + lrow;
        #pragma unroll
        for (int m = 0; m < 4; ++m) {
            const int lr = wr + m * 16 + r0;
            #pragma unroll
            for (int j = 0; j < 4; ++j) {
                float v = acc[m][n][j] + bv[n];
                if (relu) v = fmaxf(v, 0.f);
                smem[(lr + j) * 136 + lc] = f2bf(v);
            }
        }
    }
    __syncthreads();
    #pragma unroll
    for (int it = 0; it < 8; ++it) {
        const int slot = it * 256 + t;
        const int row = slot >> 4;
        const int seg = (slot & 15) * 8;
        *(ushort8_t*)(Y + (size_t)(bm + row) * M + bn + seg) =
            *(const ushort8_t*)&smem[row * 136 + seg];
    }
}

// ---------------- fused FFN: Y = relu(X@W1^T + b1) @ W2^T + b2 ------------
// 128-row tile, 256 thr = 4 waves. Loop 8 chunks of 128 ff-dims:
// GEMM1 (K=256) -> relu+bf16 pack to LDS A[128][136] -> GEMM2 (K=128) acc.
// Eliminates the 134 MB ff-intermediate HBM round trip.
// LDS: region0 [0,16384) staging dbuf; region1 [16384,33792) A tile.
__global__ __launch_bounds__(256) void k_ffn(
    const u16* __restrict__ X1, const u16* __restrict__ X2,
    const u16* __restrict__ W1a, const u16* __restrict__ W1b,
    const float* __restrict__ b1a, const float* __restrict__ b1b,
    const u16* __restrict__ W2a, const u16* __restrict__ W2b,
    const float* __restrict__ b2a, const float* __restrict__ b2b,
    u16* __restrict__ Y1, u16* __restrict__ Y2)
{
    __shared__ __align__(16) u16 smem[33792];   // 67.6 KB
    const int t = threadIdx.x;
    const int nwg = gridDim.x;           // 544, /8 = 68
    const int bid = blockIdx.x;
    const int wg = (bid & 7) * (nwg >> 3) + (bid >> 3);   // XCD-chunked
    const u16* X; const u16* W1; const float* bias1;
    const u16* W2; const float* bias2; u16* Y; int bm;
    if (wg < RT1) { X = X1; W1 = W1a; bias1 = b1a; W2 = W2a; bias2 = b2a;
                    Y = Y1; bm = wg * 128; }
    else          { X = X2; W1 = W1b; bias1 = b1b; W2 = W2b; bias2 = b2b;
                    Y = Y2; bm = (wg - RT1) * 128; }
    const int wave = t >> 6, lane = t & 63;
    const int wr  = (wave >> 1) * 64;         // GEMM1/GEMM2 row base
    const int wc  = (wave & 1) * 64;          // GEMM1 col base (ff window)
    const int wc2 = (wave & 1) * 128;         // GEMM2 col base (output)
    const int lrow = lane & 15;
    const int lg   = lane >> 4;
    const int r0   = lg * 4;

    // ---- precomputed offsets ----
    // GEMM1 staging (X rows + W1-window rows), 4 loads/wave/step
    const int src1r[2] = { (wave*2+0)*16 + (lane >> 2), (wave*2+1)*16 + (lane >> 2) };
    const int src1s[2] = { ((lane & 3) ^ ((src1r[0] >> 1) & 3)) * 8,
                           ((lane & 3) ^ ((src1r[1] >> 1) & 3)) * 8 };
    int ldsxo[2], ldswo[2];
    #pragma unroll
    for (int i = 0; i < 2; ++i) {
        ldsxo[i] = (wave * 2 + i) * 512;
        ldswo[i] = 4096 + (wave * 2 + i) * 512;
    }
    // GEMM1 frag offsets
    int aoff1[4], boff1[4];
    #pragma unroll
    for (int m = 0; m < 4; ++m) {
        const int R = wr + m * 16 + lrow;
        aoff1[m] = R * 32 + ((lg ^ ((R >> 1) & 3)) * 8);
    }
    #pragma unroll
    for (int n = 0; n < 4; ++n) {
        const int R = wc + n * 16 + lrow;
        boff1[n] = 4096 + R * 32 + ((lg ^ ((R >> 1) & 3)) * 8);
    }
    // GEMM2 W2 staging: 16 chunks of 16 rows, 4/wave/step
    int src2r[4], src2s[4], lds2o[4];
    #pragma unroll
    for (int i = 0; i < 4; ++i) {
        const int c2 = wave * 4 + i;
        src2r[i] = c2 * 16 + (lane >> 2);
        src2s[i] = ((lane & 3) ^ ((src2r[i] >> 1) & 3)) * 8;
        lds2o[i] = c2 * 512;
    }
    // GEMM2 frag offsets: A rows (region1, stride 136), W2 rows (region0)
    int aoff2[4], boff2[8];
    #pragma unroll
    for (int m = 0; m < 4; ++m)
        aoff2[m] = 16384 + (wr + m * 16 + lrow) * 136;   // + ks*32 + lg*8
    #pragma unroll
    for (int n = 0; n < 8; ++n) {
        const int R = wc2 + n * 16 + lrow;
        boff2[n] = R * 32 + ((lg ^ ((R >> 1) & 3)) * 8);
    }
    // GEMM2 output bias / epilogue cols
    float bv2[8];
    #pragma unroll
    for (int n = 0; n < 8; ++n) bv2[n] = bias2[wc2 + n * 16 + lrow];

    f32x4 acc2[4][8] = {};

    for (int ch = 0; ch < 8; ++ch) {
        // ======== GEMM1: A = relu(X @ W1_ch^T + b1_ch), 128x128, K=256 =====
        const u16* gx[2]; const u16* gw[2];
        #pragma unroll
        for (int i = 0; i < 2; ++i) {
            gx[i] = X + (size_t)(bm + src1r[i]) * 256 + src1s[i];
            gw[i] = W1 + (size_t)(ch * 128 + src1r[i]) * 256 + src1s[i];
        }
        f32x4 acc1[4][4] = {};
        #pragma unroll
        for (int i = 0; i < 2; ++i) {
            __builtin_amdgcn_global_load_lds(gx[i], &smem[ldsxo[i]], 16, 0, 0);
            __builtin_amdgcn_global_load_lds(gw[i], &smem[ldswo[i]], 16, 0, 0);
            gx[i] += 32; gw[i] += 32;
        }
        __syncthreads();
        int cur = 0;
        #pragma unroll
        for (int ts = 0; ts < 8; ++ts) {
            if (ts + 1 < 8) {
                const int nb = (cur ^ 1) * BUF_U16;
                #pragma unroll
                for (int i = 0; i < 2; ++i) {
                    __builtin_amdgcn_global_load_lds(gx[i], &smem[nb + ldsxo[i]], 16, 0, 0);
                    __builtin_amdgcn_global_load_lds(gw[i], &smem[nb + ldswo[i]], 16, 0, 0);
                    gx[i] += 32; gw[i] += 32;
                }
            }
            const int cb = cur * BUF_U16;
            short8_t a[4], b[4];
            #pragma unroll
            for (int m = 0; m < 4; ++m) a[m] = *(const short8_t*)&smem[cb + aoff1[m]];
            #pragma unroll
            for (int n = 0; n < 4; ++n) b[n] = *(const short8_t*)&smem[cb + boff1[n]];
            #pragma unroll
            for (int m = 0; m < 4; ++m)
                #pragma unroll
                for (int n = 0; n < 4; ++n)
                    acc1[m][n] = __builtin_amdgcn_mfma_f32_16x16x32_bf16(
                        a[m], b[n], acc1[m][n], 0, 0, 0);
            __syncthreads();
            cur ^= 1;
        }

        // ======== stage W2 ks=0 (region0 free now) + pack A ================
        const u16* gw2[4];
        #pragma unroll
        for (int i = 0; i < 4; ++i)
            gw2[i] = W2 + (size_t)src2r[i] * 1024 + ch * 128 + src2s[i];
        #pragma unroll
        for (int i = 0; i < 4; ++i) {
            __builtin_amdgcn_global_load_lds(gw2[i], &smem[lds2o[i]], 16, 0, 0);
            gw2[i] += 32;
        }
        // pack A = relu(acc1 + b1) as bf16 (identical rounding to old ff1 out)
        #pragma unroll
        for (int n = 0; n < 4; ++n) {
            const float bv1 = bias1[ch * 128 + wc + n * 16 + lrow];
            const int lc = wc + n * 16 + lrow;
            #pragma unroll
            for (int m = 0; m < 4; ++m) {
                const int lr = wr + m * 16 + r0;
                #pragma unroll
                for (int j = 0; j < 4; ++j) {
                    const float v = fmaxf(acc1[m][n][j] + bv1, 0.f);
                    smem[16384 + (lr + j) * 136 + lc] = f2bf(v);
                }
            }
        }
        __syncthreads();    // drains W2 ks0 loads + joins A pack

        // ======== GEMM2: acc2 += A @ W2_ch^T, K=128 ========================
        cur = 0;
        #pragma unroll
        for (int ks = 0; ks < 4; ++ks) {
            if (ks + 1 < 4) {
                const int nb = (cur ^ 1) * BUF_U16;
                #pragma unroll
                for (int i = 0; i < 4; ++i) {
                    __builtin_amdgcn_global_load_lds(gw2[i], &smem[nb + lds2o[i]], 16, 0, 0);
                    gw2[i] += 32;
                }
            }
            const int cb = cur * BUF_U16;
            short8_t a[4], b[8];
            #pragma unroll
            for (int m = 0; m < 4; ++m)
                a[m] = *(const short8_t*)&smem[aoff2[m] + ks * 32 + lg * 8];
            #pragma unroll
            for (int n = 0; n < 8; ++n)
                b[n] = *(const short8_t*)&smem[cb + boff2[n]];
            #pragma unroll
            for (int m = 0; m < 4; ++m)
                #pragma unroll
                for (int n = 0; n < 8; ++n)
                    acc2[m][n] = __builtin_amdgcn_mfma_f32_16x16x32_bf16(
                        a[m], b[n], acc2[m][n], 0, 0, 0);
            __syncthreads();
            cur ^= 1;
        }
        // after last sync: region0 + A both reusable by next chunk
    }

    // ======== epilogue: Y = acc2 + b2, stage [128][264], coalesced store ===
    #pragma unroll
    for (int n = 0; n < 8; ++n) {
        const int lc = wc2 + n * 16 + lrow;        // 0..255
        #pragma unroll
        for (int m = 0; m < 4; ++m) {
            const int lr = wr + m * 16 + r0;
            #pragma unroll
            for (int j = 0; j < 4; ++j)
                smem[(lr + j) * 264 + lc] = f2bf(acc2[m][n][j] + bv2[n]);
        }
    }
    __syncthreads();
    #pragma unroll
    for (int it = 0; it < 16; ++it) {
        const int slot = it * 256 + t;     // 4096 slots = 128 rows x 32 segs
        const int row = slot >> 5;
        const int seg = (slot & 31) * 8;
        *(ushort8_t*)(Y + (size_t)(bm + row) * 256 + seg) =
            *(const ushort8_t*)&smem[row * 264 + seg];
    }
}

// ---------------- MFMA flash attention, merged encoders -------------------
__global__ __launch_bounds__(256) void k_attn_mfma(
    const u16* __restrict__ qkv1, const u16* __restrict__ qkv2,
    const int* __restrict__ tok1, const int* __restrict__ tok2,
    u16* __restrict__ out1, u16* __restrict__ out2)
{
    __shared__ __align__(16) u16 Ks[128][40];    // K rows [key][d]
    __shared__ __align__(16) u16 Vt[32][136];    // V transposed [d][key]
    __shared__ __align__(16) u16 Pl[128][40];    // P chunk [q][key%32] per wave
    __shared__ int msk[128];
    const int t = threadIdx.x;
    const int wave = t >> 6, lane = t & 63;
    const int lq = lane & 15, lg = lane >> 4;
    const int bid = blockIdx.x;
    const u16* qkv; const int* tok; u16* out;
    int L, Bv, b, h, qt;
    if (bid < B1 * NH) {
        qkv = qkv1; tok = tok1; out = out1; L = L1; Bv = B1;
        qt = 0; b = bid >> 3; h = bid & 7;
    } else {
        const int r = bid - B1 * NH;
        qkv = qkv2; tok = tok2; out = out2; L = L2; Bv = B2;
        qt = r >> 6; const int bh = r & 63; b = bh >> 3; h = bh & 7;
    }
    const int q0 = qt * 128 + wave * 32;

    short8_t qf[2];
    #pragma unroll
    for (int n = 0; n < 2; ++n)
        qf[n] = *(const short8_t*)(qkv +
            (size_t)((q0 + n * 16 + lq) * Bv + b) * 768 + h * DH + lg * 8);

    f32x4 o[2][2] = {};
    float mrun[2] = {-1e9f, -1e9f};
    float lrun[2] = {0.f, 0.f};

    for (int kt = 0; kt < L; kt += 128) {
        #pragma unroll
        for (int it = 0; it < 2; ++it) {
            const int slot = t + it * 256;
            const int row = slot >> 2;
            const int seg = (slot & 3) * 8;
            const u16* base = qkv + (size_t)((kt + row) * Bv + b) * 768 + 256 + h * DH + seg;
            *(ushort8_t*)&Ks[row][seg] = *(const ushort8_t*)base;
            const ushort8_t v8 = *(const ushort8_t*)(base + 256);
            #pragma unroll
            for (int e = 0; e < 8; ++e) Vt[seg + e][row] = v8[e];
        }
        if (t < 128) msk[t] = tok[(size_t)(kt + t) * Bv + b];
        __syncthreads();

        uint2 preg[2][8];                 // packed P, static-indexed
        #pragma unroll
        for (int n = 0; n < 2; ++n) {
            f32x4 s[8];
            #pragma unroll
            for (int mp = 0; mp < 8; ++mp) {
                const short8_t kf = *(const short8_t*)&Ks[mp * 16 + lq][lg * 8];
                s[mp] = __builtin_amdgcn_mfma_f32_16x16x32_bf16(
                    kf, qf[n], (f32x4){0.f, 0.f, 0.f, 0.f}, 0, 0, 0);
            }
            float mx = -3.0e38f;
            #pragma unroll
            for (int mp = 0; mp < 8; ++mp) {
                #pragma unroll
                for (int j = 0; j < 4; ++j) {
                    float v = s[mp][j];                        // pre-scaled (base-2)
                    v = (msk[mp * 16 + lg * 4 + j] == 0) ? -1e9f : v;
                    s[mp][j] = v;
                    mx = fmaxf(mx, v);
                }
            }
            mx = fmaxf(mx, __shfl_xor(mx, 16));
            mx = fmaxf(mx, __shfl_xor(mx, 32));
            const float mnew = fmaxf(mrun[n], mx);
            const float fac = exp2f(mrun[n] - mnew);
            mrun[n] = mnew;
            lrun[n] *= fac;
            #pragma unroll
            for (int dt = 0; dt < 2; ++dt)
                #pragma unroll
                for (int j = 0; j < 4; ++j) o[dt][n][j] *= fac;
            float lsum = 0.f;
            #pragma unroll
            for (int mp = 0; mp < 8; ++mp) {
                const float p0 = exp2f(s[mp][0] - mnew);
                const float p1 = exp2f(s[mp][1] - mnew);
                const float p2 = exp2f(s[mp][2] - mnew);
                const float p3 = exp2f(s[mp][3] - mnew);
                lsum += (p0 + p1) + (p2 + p3);
                preg[n][mp].x = cvt_pk_bf16(p0, p1);
                preg[n][mp].y = cvt_pk_bf16(p2, p3);
            }
            lsum += __shfl_xor(lsum, 16);
            lsum += __shfl_xor(lsum, 32);
            lrun[n] += lsum;
        }

        // PV: stream 32-key chunks through wave-private Pl rows (no barrier)
        #pragma unroll
        for (int kk = 0; kk < 4; ++kk) {
            #pragma unroll
            for (int n = 0; n < 2; ++n) {
                u16* prow = &Pl[wave * 32 + n * 16 + lq][0];
                *(uint2*)(prow + lg * 4)      = preg[n][2 * kk];
                *(uint2*)(prow + 16 + lg * 4) = preg[n][2 * kk + 1];
            }
            short8_t pf[2];
            #pragma unroll
            for (int n = 0; n < 2; ++n)
                pf[n] = *(const short8_t*)&Pl[wave * 32 + n * 16 + lq][lg * 8];
            #pragma unroll
            for (int dt = 0; dt < 2; ++dt) {
                const short8_t vf = *(const short8_t*)&Vt[dt * 16 + lq][kk * 32 + lg * 8];
                #pragma unroll
                for (int n = 0; n < 2; ++n)
                    o[dt][n] = __builtin_amdgcn_mfma_f32_16x16x32_bf16(
                        vf, pf[n], o[dt][n], 0, 0, 0);
            }
        }
        __syncthreads();
    }

    #pragma unroll
    for (int n = 0; n < 2; ++n) {
        const float inv = 1.f / lrun[n];
        const int q = q0 + n * 16 + lq;
        u16* op = out + (size_t)(q * Bv + b) * H + h * DH;
        #pragma unroll
        for (int dt = 0; dt < 2; ++dt)
            #pragma unroll
            for (int jj = 0; jj < 2; ++jj) {
                const unsigned pk = cvt_pk_bf16(o[dt][n][jj*2] * inv,
                                                o[dt][n][jj*2+1] * inv);
                *(unsigned*)(op + dt * 16 + lg * 4 + jj * 2) = pk;
            }
    }
}

// ---------------- merged residual + LayerNorm (bf16 out, to ws) -----------
__global__ __launch_bounds__(256) void k_add_ln(
    const u16* __restrict__ x1, const u16* __restrict__ x2,
    const u16* __restrict__ r1, const u16* __restrict__ r2,
    const float* __restrict__ gs1, const float* __restrict__ gs2,
    const float* __restrict__ gb1, const float* __restrict__ gb2,
    u16* __restrict__ y1, u16* __restrict__ y2)
{
    const int wave = threadIdx.x >> 6, lane = threadIdx.x & 63;
    size_t row = (size_t)blockIdx.x * 4 + wave;
    const u16 *x, *r; const float *gs, *gb; u16* y;
    if (row < N1) { x = x1; r = r1; gs = gs1; gb = gb1; y = y1; }
    else { row -= N1; x = x2; r = r2; gs = gs2; gb = gb2; y = y2; }
    const int c = lane * 4;
    const ushort4_t xv = *(const ushort4_t*)(x + row * H + c);
    const ushort4_t rv = *(const ushort4_t*)(r + row * H + c);
    float v[4] = { bf2f(xv.x) + bf2f(rv.x), bf2f(xv.y) + bf2f(rv.y),
                   bf2f(xv.z) + bf2f(rv.z), bf2f(xv.w) + bf2f(rv.w) };
    float sum = v[0] + v[1] + v[2] + v[3];
    float sq  = v[0]*v[0] + v[1]*v[1] + v[2]*v[2] + v[3]*v[3];
    #pragma unroll
    for (int off = 1; off < 64; off <<= 1) {
        sum += __shfl_xor(sum, off);
        sq  += __shfl_xor(sq, off);
    }
    const float mean = sum * (1.f / H);
    const float var  = sq * (1.f / H) - mean * mean;
    const float is   = rsqrtf(var + 1e-5f);
    const float4 sv = *(const float4*)(gs + c);
    const float4 bv = *(const float4*)(gb + c);
    ushort4_t o;
    o.x = f2bf((v[0] - mean) * is * sv.x + bv.x);
    o.y = f2bf((v[1] - mean) * is * sv.y + bv.y);
    o.z = f2bf((v[2] - mean) * is * sv.z + bv.z);
    o.w = f2bf((v[3] - mean) * is * sv.w + bv.w);
    *(ushort4_t*)(y + row * H + c) = o;
}

// ---------------- merged residual + LayerNorm (f32 out, to d_out) ---------
__global__ __launch_bounds__(256) void k_add_ln_f32(
    const u16* __restrict__ x1, const u16* __restrict__ x2,
    const u16* __restrict__ r1, const u16* __restrict__ r2,
    const float* __restrict__ gs1, const float* __restrict__ gs2,
    const float* __restrict__ gb1, const float* __restrict__ gb2,
    float* __restrict__ y)
{
    const int wave = threadIdx.x >> 6, lane = threadIdx.x & 63;
    const size_t grow = (size_t)blockIdx.x * 4 + wave;
    const int c = lane * 4;
    float* yp = y + grow * H + c;
    size_t row = grow;
    const u16 *x, *r; const float *gs, *gb;
    if (row < N1) { x = x1; r = r1; gs = gs1; gb = gb1; }
    else { row -= N1; x = x2; r = r2; gs = gs2; gb = gb2; }
    const ushort4_t xv = *(const ushort4_t*)(x + row * H + c);
    const ushort4_t rv = *(const ushort4_t*)(r + row * H + c);
    float v[4] = { bf2f(xv.x) + bf2f(rv.x), bf2f(xv.y) + bf2f(rv.y),
                   bf2f(xv.z) + bf2f(rv.z), bf2f(xv.w) + bf2f(rv.w) };
    float sum = v[0] + v[1] + v[2] + v[3];
    float sq  = v[0]*v[0] + v[1]*v[1] + v[2]*v[2] + v[3]*v[3];
    #pragma unroll
    for (int off = 1; off < 64; off <<= 1) {
        sum += __shfl_xor(sum, off);
        sq  += __shfl_xor(sq, off);
    }
    const float mean = sum * (1.f / H);
    const float var  = sq * (1.f / H) - mean * mean;
    const float is   = rsqrtf(var + 1e-5f);
    const float4 sv = *(const float4*)(gs + c);
    const float4 bv = *(const float4*)(gb + c);
    float4 o;
    o.x = (v[0] - mean) * is * sv.x + bv.x;
    o.y = (v[1] - mean) * is * sv.y + bv.y;
    o.z = (v[2] - mean) * is * sv.z + bv.z;
    o.w = (v[3] - mean) * is * sv.w + bv.w;
    *(float4*)yp = o;
}

// --------------------------------------------------------------------------
extern "C" void kernel_launch(void* const* d_in, const int* in_sizes, int n_in,
                              void* d_out, int out_size, void* d_ws, size_t ws_size,
                              hipStream_t stream)
{
    const int* units = (const int*)d_in[0];
    const int* paths = (const int*)d_in[1];
    const float* emb = (const float*)d_in[4];          // f32 inputs
    const float* const* ep = (const float* const*)(d_in + 5);
    const float* const* od = (const float* const*)(d_in + 17);
    float* out = (float*)d_out;                        // f32 output

    // workspace (~220 MB): separate enc1/enc2 activations + bf16 weights
    u16* bufX1   = (u16*)d_ws;
    u16* bufX2   = bufX1 + (size_t)N1 * H;
    u16* bufBig1 = bufX2 + (size_t)N2 * H;
    u16* bufBig2 = bufBig1 + (size_t)N1 * FFDIM;
    u16* bufO1   = bufBig2 + (size_t)N2 * FFDIM;
    u16* bufO2   = bufO1 + (size_t)N1 * H;
    int* tokb1   = (int*)(bufO2 + (size_t)N2 * H);
    int* tokb2   = tokb1 + N1;
    u16* wbuf    = (u16*)(tokb2 + N2);                 // 2*encstride bf16
    const int wqkv = 2 * 768 * H, wout = 2 * H * H,
              wff1 = 2 * FFDIM * H, wff2 = 2 * H * FFDIM;
    const int encstride = wqkv + wout + wff1 + wff2;   // 1572864
    float* qbias = (float*)(wbuf + 2 * (size_t)encstride);  // 3072 f32 scaled

    // one dispatch converts all 8 weight matrices (Q rows pre-scaled)
    k_f2bf8<<<(2 * encstride) / 1024, 256, 0, stream>>>(
        ep[0], ep[2], ep[6], ep[8], od[0], od[2], od[6], od[8], wbuf);
    // scaled qkv biases (f32)
    k_scaleb<<<12, 256, 0, stream>>>(ep[1], od[1], qbias);

    // merged gather
    k_gather<<<(N1 + N2) / 4, 256, 0, stream>>>(units, paths, emb,
                                                bufX1, bufX2, tokb1, tokb2);

    for (int layer = 0; layer < 2; ++layer) {
        const u16* wb1 = wbuf;
        const u16* wb2 = wbuf + (size_t)encstride;
        const u16* qkvw1 = wb1 + (size_t)layer * 768 * H;
        const u16* qkvw2 = wb2 + (size_t)layer * 768 * H;
        const u16* outw1 = wb1 + wqkv + (size_t)layer * H * H;
        const u16* outw2 = wb2 + wqkv + (size_t)layer * H * H;
        const u16* ff1w1 = wb1 + wqkv + wout + (size_t)layer * FFDIM * H;
        const u16* ff1w2 = wb2 + wqkv + wout + (size_t)layer * FFDIM * H;
        const u16* ff2w1 = wb1 + wqkv + wout + wff1 + (size_t)layer * H * FFDIM;
        const u16* ff2w2 = wb2 + wqkv + wout + wff1 + (size_t)layer * H * FFDIM;
        const float* qkvb1 = qbias + (size_t)layer * 768;
        const float* qkvb2 = qbias + 1536 + (size_t)layer * 768;
        const float* outb1 = ep[3] + (size_t)layer * H;
        const float* outb2 = od[3] + (size_t)layer * H;
        const float* ln1s1 = ep[4] + (size_t)layer * H;
        const float* ln1s2 = od[4] + (size_t)layer * H;
        const float* ln1b1 = ep[5] + (size_t)layer * H;
        const float* ln1b2 = od[5] + (size_t)layer * H;
        const float* ff1b1 = ep[7] + (size_t)layer * FFDIM;
        const float* ff1b2 = od[7] + (size_t)layer * FFDIM;
        const float* ff2b1 = ep[9] + (size_t)layer * H;
        const float* ff2b2 = od[9] + (size_t)layer * H;
        const float* ln2s1 = ep[10] + (size_t)layer * H;
        const float* ln2s2 = od[10] + (size_t)layer * H;
        const float* ln2b1 = ep[11] + (size_t)layer * H;
        const float* ln2b2 = od[11] + (size_t)layer * H;

        // qkv projection (merged; Q pre-scaled via weights/bias)
        k_gemm_mfma<<<(RT1 + RT2) * (768 / 128), 256, 0, stream>>>(
            bufX1, bufX2, qkvw1, qkvw2, qkvb1, qkvb2, bufBig1, bufBig2, H, 768, 0);
        // attention (merged)
        k_attn_mfma<<<B1 * NH + B2 * NH * (L2 / 128), 256, 0, stream>>>(
            bufBig1, bufBig2, tokb1, tokb2, bufO1, bufO2);
        // out-proj (merged)
        k_gemm_mfma<<<(RT1 + RT2) * (H / 128), 256, 0, stream>>>(
            bufO1, bufO2, outw1, outw2, outb1, outb2, bufBig1, bufBig2, H, H, 0);
        // x = LN(x + attnproj) (merged)
        k_add_ln<<<(N1 + N2) / 4, 256, 0, stream>>>(
            bufX1, bufX2, bufBig1, bufBig2, ln1s1, ln1s2, ln1b1, ln1b2, bufX1, bufX2);
        // fused FFN: bufO = relu(bufX@W1^T+b1)@W2^T + b2  (no ff intermediate)
        k_ffn<<<RT1 + RT2, 256, 0, stream>>>(
            bufX1, bufX2, ff1w1, ff1w2, ff1b1, ff1b2,
            ff2w1, ff2w2, ff2b1, ff2b2, bufO1, bufO2);
        // x = LN(x + ff)
        if (layer == 1)
            k_add_ln_f32<<<(N1 + N2) / 4, 256, 0, stream>>>(
                bufX1, bufX2, bufO1, bufO2, ln2s1, ln2s2, ln2b1, ln2b2, out);
        else
            k_add_ln<<<(N1 + N2) / 4, 256, 0, stream>>>(
                bufX1, bufX2, bufO1, bufO2, ln2s1, ln2s2, ln2b1, ln2b2, bufX1, bufX2);
    }
}

// Round 19
// 562.671 us; speedup vs baseline: 1.1737x; 1.1737x over previous
//
#include <hip/hip_runtime.h>
#include <math.h>

// Problem constants (fixed by setup_inputs: B=8, UPD=32, PPD=64)
#define H      256
#define NH     8
#define DH     32
#define FFDIM  1024
#define L1     128      // DEPTH*UNIT_LEN
#define B1     512      // B*PPD
#define L2     512      // UPD*UNIT_LEN
#define B2     8        // nb
#define N1     (L1*B1)  // 65536
#define N2     (L2*B2)  // 4096
#define RT1    (N1/128) // 512 row tiles enc1
#define RT2    (N2/128) // 32 row tiles enc2
#define QSCL   0.25506602273492887f   // (1/sqrt(32)) * log2(e)

typedef unsigned short u16;
typedef unsigned short ushort4_t __attribute__((ext_vector_type(4)));
typedef unsigned short ushort8_t __attribute__((ext_vector_type(8)));
typedef short          short8_t  __attribute__((ext_vector_type(8)));
typedef float          f32x4     __attribute__((ext_vector_type(4)));

__device__ __forceinline__ float bf2f(u16 u) {
    union { unsigned int i; float f; } v; v.i = ((unsigned int)u) << 16; return v.f;
}
__device__ __forceinline__ u16 f2bf(float f) {
    union { float f; unsigned int i; } v; v.f = f;
    unsigned int x = v.i;
    return (u16)((x + 0x7fffu + ((x >> 16) & 1u)) >> 16);   // RNE
}
__device__ __forceinline__ unsigned cvt_pk_bf16(float lo, float hi) {
    unsigned r;
    asm("v_cvt_pk_bf16_f32 %0, %1, %2" : "=v"(r) : "v"(lo), "v"(hi));
    return r;                                     // lo in [15:0], hi in [31:16], RNE
}

// ---------------- merged f32 -> bf16 weight preconvert (1 dispatch) -------
__global__ __launch_bounds__(256) void k_f2bf8(
    const float* __restrict__ s0, const float* __restrict__ s1,
    const float* __restrict__ s2, const float* __restrict__ s3,
    const float* __restrict__ s4, const float* __restrict__ s5,
    const float* __restrict__ s6, const float* __restrict__ s7,
    u16* __restrict__ out)
{
    const int cums[9] = {0, 393216, 524288, 1048576, 1572864,
                         1966080, 2097152, 2621440, 3145728};
    const float* srcs[8] = {s0, s1, s2, s3, s4, s5, s6, s7};
    const int gbase = blockIdx.x * 1024;          // block-uniform segment
    int seg = 0;
    #pragma unroll
    for (int i = 1; i < 8; ++i) if (gbase >= cums[i]) seg = i;
    const int idx = gbase + threadIdx.x * 4;
    const int off = idx - cums[seg];
    const float fs = ((seg == 0 || seg == 4) && (off % 196608) < 65536)
                   ? QSCL : 1.0f;
    const float4 v = *(const float4*)(srcs[seg] + off);
    ushort4_t o;
    o.x = f2bf(v.x * fs); o.y = f2bf(v.y * fs);
    o.z = f2bf(v.z * fs); o.w = f2bf(v.w * fs);
    *(ushort4_t*)(out + idx) = o;
}

// ---------------- scaled qkv bias copy (Q cols x QSCL), f32 ---------------
__global__ __launch_bounds__(256) void k_scaleb(
    const float* __restrict__ b1, const float* __restrict__ b2,
    float* __restrict__ out)
{
    const int i = blockIdx.x * 256 + threadIdx.x;  // 0..3071
    const float* src = (i < 1536) ? b1 : b2;
    const int j = (i < 1536) ? i : i - 1536;
    float v = src[j];
    if ((j % 768) < 256) v *= QSCL;
    out[i] = v;
}

// ---------------- merged gather + embedding + PE (both encoders) ----------
__global__ __launch_bounds__(256) void k_gather(
    const int* __restrict__ units, const int* __restrict__ paths,
    const float* __restrict__ emb,
    u16* __restrict__ x1, u16* __restrict__ x2,
    int* __restrict__ tokb1, int* __restrict__ tokb2)
{
    const int wave = threadIdx.x >> 6, lane = threadIdx.x & 63;
    const int t = blockIdx.x * 4 + wave;
    int tokid, l;
    u16* xp; int* tokp;
    if (t < N1) {                       // enc1: ctx gather
        l = t / B1; const int b = t - l * B1;
        const int d = l >> 4, u = l & 15;
        const int col = (b >> 6) * 32 + paths[d * 512 + b];
        tokid = units[u * 256 + col];
        xp = x1 + (size_t)t * H; tokp = tokb1 + t;
    } else {                            // enc2: order gather
        const int t2 = t - N1;
        l = t2 / B2; const int b = t2 - l * B2;
        const int w = l >> 4, u = l & 15;
        tokid = units[u * 256 + b * 32 + w];
        xp = x2 + (size_t)t2 * H; tokp = tokb2 + t2;
    }
    if (lane == 0) *tokp = tokid;
    const int c = lane * 4;
    const float4 e = *(const float4*)(emb + (size_t)tokid * H + c);
    const float i0 = (float)(c >> 1);
    const float a0 = (float)l * expf(-0.07195578415606394f * i0);
    const float a1 = (float)l * expf(-0.07195578415606394f * (i0 + 1.0f));
    ushort4_t o;
    o.x = f2bf(e.x + sinf(a0));
    o.y = f2bf(e.y + cosf(a0));
    o.z = f2bf(e.z + sinf(a1));
    o.w = f2bf(e.w + cosf(a1));
    *(ushort4_t*)(xp + c) = o;
}

// ---------------- MFMA GEMM 128x128 (round-8 core), merged encoders -------
// Single-pass epilogue: full 128x128 tile staged at stride 136, 1 barrier.
#define BUF_U16 8192      // one buffer: X[128][32] + W[128][32] = 16 KB
__global__ __launch_bounds__(256) void k_gemm_mfma(
    const u16* __restrict__ X1, const u16* __restrict__ X2,
    const u16* __restrict__ W1, const u16* __restrict__ W2,
    const float* __restrict__ b1, const float* __restrict__ b2,
    u16* __restrict__ Y1, u16* __restrict__ Y2,
    int K, int M, int relu)
{
    __shared__ __align__(16) u16 smem[17408];   // K-loop uses [0,16384)
    const int t = threadIdx.x;
    const int mtiles = M >> 7;
    const int nwg = gridDim.x;
    const int bid = blockIdx.x;
    const int wg = (bid & 7) * (nwg >> 3) + (bid >> 3);   // XCD-chunked
    const int rt = wg / mtiles;
    const int bn = (wg % mtiles) * 128;
    const u16* X; const u16* W; const float* bias; u16* Y; int bm;
    if (rt < RT1) { X = X1; W = W1; bias = b1; Y = Y1; bm = rt * 128; }
    else          { X = X2; W = W2; bias = b2; Y = Y2; bm = (rt - RT1) * 128; }
    const int wave = t >> 6, lane = t & 63;
    const int wr = (wave >> 1) * 64, wc = (wave & 1) * 64;
    const int lrow = lane & 15;
    const int lg   = lane >> 4;

    const u16* gx[2]; const u16* gw[2];
    int ldsxo[2], ldswo[2];
    #pragma unroll
    for (int i = 0; i < 2; ++i) {
        const int c = wave * 2 + i;
        const int r = c * 16 + (lane >> 2);
        const int s = (lane & 3) ^ ((r >> 1) & 3);
        gx[i] = X + (size_t)(bm + r) * K + s * 8;
        gw[i] = W + (size_t)(bn + r) * K + s * 8;
        ldsxo[i] = c * 512;
        ldswo[i] = 4096 + c * 512;
    }
    int aoff[4], boff[4];
    #pragma unroll
    for (int m = 0; m < 4; ++m) {
        const int R = wr + m * 16 + lrow;
        aoff[m] = R * 32 + ((lg ^ ((R >> 1) & 3)) * 8);
    }
    #pragma unroll
    for (int n = 0; n < 4; ++n) {
        const int R = wc + n * 16 + lrow;
        boff[n] = 4096 + R * 32 + ((lg ^ ((R >> 1) & 3)) * 8);
    }

    f32x4 acc[4][4] = {};
    const int nt = K >> 5;

    #pragma unroll
    for (int i = 0; i < 2; ++i) {
        __builtin_amdgcn_global_load_lds(gx[i], &smem[ldsxo[i]], 16, 0, 0);
        __builtin_amdgcn_global_load_lds(gw[i], &smem[ldswo[i]], 16, 0, 0);
        gx[i] += 32; gw[i] += 32;
    }
    __syncthreads();

    int cur = 0;
    for (int ts = 0; ts < nt; ++ts) {
        if (ts + 1 < nt) {
            const int nb = (cur ^ 1) * BUF_U16;
            #pragma unroll
            for (int i = 0; i < 2; ++i) {
                __builtin_amdgcn_global_load_lds(gx[i], &smem[nb + ldsxo[i]], 16, 0, 0);
                __builtin_amdgcn_global_load_lds(gw[i], &smem[nb + ldswo[i]], 16, 0, 0);
                gx[i] += 32; gw[i] += 32;
            }
        }
        const int cb = cur * BUF_U16;
        short8_t a[4], b[4];
        #pragma unroll
        for (int m = 0; m < 4; ++m) a[m] = *(const short8_t*)&smem[cb + aoff[m]];
        #pragma unroll
        for (int n = 0; n < 4; ++n) b[n] = *(const short8_t*)&smem[cb + boff[n]];
        #pragma unroll
        for (int m = 0; m < 4; ++m)
            #pragma unroll
            for (int n = 0; n < 4; ++n)
                acc[m][n] = __builtin_amdgcn_mfma_f32_16x16x32_bf16(
                    a[m], b[n], acc[m][n], 0, 0, 0);
        __syncthreads();
        cur ^= 1;
    }

    // bias (C frag: col = lane&15, row = (lane>>4)*4 + j)
    float bv[4];
    #pragma unroll
    for (int n = 0; n < 4; ++n) bv[n] = bias[bn + wc + n * 16 + lrow];
    const int r0 = (lane >> 4) * 4;

    // single-pass epilogue: all waves stage their sub-tiles, 1 barrier, store
    #pragma unroll
    for (int n = 0; n < 4; ++n) {
        const int lc = wc + n * 16 + lrow;         // 0..127 within tile
        #pragma unroll
        for (int m = 0; m < 4; ++m) {
            const int lr = wr + m * 16 + r0;
            #pragma unroll
            for (int j = 0; j < 4; ++j) {
                float v = acc[m][n][j] + bv[n];
                if (relu) v = fmaxf(v, 0.f);
                smem[(lr + j) * 136 + lc] = f2bf(v);
            }
        }
    }
    __syncthreads();
    #pragma unroll
    for (int it = 0; it < 8; ++it) {
        const int slot = it * 256 + t;     // 2048 slots = 128 rows x 16 segs
        const int row = slot >> 4;
        const int seg = (slot & 15) * 8;
        *(ushort8_t*)(Y + (size_t)(bm + row) * M + bn + seg) =
            *(const ushort8_t*)&smem[row * 136 + seg];
    }
}

// ---------------- MFMA flash attention, merged encoders -------------------
// Q pre-scaled by (1/sqrt(DH))*log2(e) -> base-2 softmax. Packed P held in
// registers; PV streams 32-key chunks through a small wave-private Pl.
__global__ __launch_bounds__(256) void k_attn_mfma(
    const u16* __restrict__ qkv1, const u16* __restrict__ qkv2,
    const int* __restrict__ tok1, const int* __restrict__ tok2,
    u16* __restrict__ out1, u16* __restrict__ out2)
{
    __shared__ __align__(16) u16 Ks[128][40];    // K rows [key][d]
    __shared__ __align__(16) u16 Vt[32][136];    // V transposed [d][key]
    __shared__ __align__(16) u16 Pl[128][40];    // P chunk [q][key%32] per wave
    __shared__ int msk[128];
    const int t = threadIdx.x;
    const int wave = t >> 6, lane = t & 63;
    const int lq = lane & 15, lg = lane >> 4;
    const int bid = blockIdx.x;
    const u16* qkv; const int* tok; u16* out;
    int L, Bv, b, h, qt;
    if (bid < B1 * NH) {
        qkv = qkv1; tok = tok1; out = out1; L = L1; Bv = B1;
        qt = 0; b = bid >> 3; h = bid & 7;
    } else {
        const int r = bid - B1 * NH;
        qkv = qkv2; tok = tok2; out = out2; L = L2; Bv = B2;
        qt = r >> 6; const int bh = r & 63; b = bh >> 3; h = bh & 7;
    }
    const int q0 = qt * 128 + wave * 32;

    short8_t qf[2];
    #pragma unroll
    for (int n = 0; n < 2; ++n)
        qf[n] = *(const short8_t*)(qkv +
            (size_t)((q0 + n * 16 + lq) * Bv + b) * 768 + h * DH + lg * 8);

    f32x4 o[2][2] = {};
    float mrun[2] = {-1e9f, -1e9f};
    float lrun[2] = {0.f, 0.f};

    for (int kt = 0; kt < L; kt += 128) {
        #pragma unroll
        for (int it = 0; it < 2; ++it) {
            const int slot = t + it * 256;
            const int row = slot >> 2;
            const int seg = (slot & 3) * 8;
            const u16* base = qkv + (size_t)((kt + row) * Bv + b) * 768 + 256 + h * DH + seg;
            *(ushort8_t*)&Ks[row][seg] = *(const ushort8_t*)base;
            const ushort8_t v8 = *(const ushort8_t*)(base + 256);
            #pragma unroll
            for (int e = 0; e < 8; ++e) Vt[seg + e][row] = v8[e];
        }
        if (t < 128) msk[t] = tok[(size_t)(kt + t) * Bv + b];
        __syncthreads();

        uint2 preg[2][8];                 // packed P, static-indexed
        #pragma unroll
        for (int n = 0; n < 2; ++n) {
            f32x4 s[8];
            #pragma unroll
            for (int mp = 0; mp < 8; ++mp) {
                const short8_t kf = *(const short8_t*)&Ks[mp * 16 + lq][lg * 8];
                s[mp] = __builtin_amdgcn_mfma_f32_16x16x32_bf16(
                    kf, qf[n], (f32x4){0.f, 0.f, 0.f, 0.f}, 0, 0, 0);
            }
            float mx = -3.0e38f;
            #pragma unroll
            for (int mp = 0; mp < 8; ++mp) {
                #pragma unroll
                for (int j = 0; j < 4; ++j) {
                    float v = s[mp][j];                        // pre-scaled (base-2)
                    v = (msk[mp * 16 + lg * 4 + j] == 0) ? -1e9f : v;
                    s[mp][j] = v;
                    mx = fmaxf(mx, v);
                }
            }
            mx = fmaxf(mx, __shfl_xor(mx, 16));
            mx = fmaxf(mx, __shfl_xor(mx, 32));
            const float mnew = fmaxf(mrun[n], mx);
            const float fac = exp2f(mrun[n] - mnew);
            mrun[n] = mnew;
            lrun[n] *= fac;
            #pragma unroll
            for (int dt = 0; dt < 2; ++dt)
                #pragma unroll
                for (int j = 0; j < 4; ++j) o[dt][n][j] *= fac;
            float lsum = 0.f;
            #pragma unroll
            for (int mp = 0; mp < 8; ++mp) {
                const float p0 = exp2f(s[mp][0] - mnew);
                const float p1 = exp2f(s[mp][1] - mnew);
                const float p2 = exp2f(s[mp][2] - mnew);
                const float p3 = exp2f(s[mp][3] - mnew);
                lsum += (p0 + p1) + (p2 + p3);
                preg[n][mp].x = cvt_pk_bf16(p0, p1);
                preg[n][mp].y = cvt_pk_bf16(p2, p3);
            }
            lsum += __shfl_xor(lsum, 16);
            lsum += __shfl_xor(lsum, 32);
            lrun[n] += lsum;
        }

        // PV: stream 32-key chunks through wave-private Pl rows (no barrier)
        #pragma unroll
        for (int kk = 0; kk < 4; ++kk) {
            #pragma unroll
            for (int n = 0; n < 2; ++n) {
                u16* prow = &Pl[wave * 32 + n * 16 + lq][0];
                *(uint2*)(prow + lg * 4)      = preg[n][2 * kk];
                *(uint2*)(prow + 16 + lg * 4) = preg[n][2 * kk + 1];
            }
            short8_t pf[2];
            #pragma unroll
            for (int n = 0; n < 2; ++n)
                pf[n] = *(const short8_t*)&Pl[wave * 32 + n * 16 + lq][lg * 8];
            #pragma unroll
            for (int dt = 0; dt < 2; ++dt) {
                const short8_t vf = *(const short8_t*)&Vt[dt * 16 + lq][kk * 32 + lg * 8];
                #pragma unroll
                for (int n = 0; n < 2; ++n)
                    o[dt][n] = __builtin_amdgcn_mfma_f32_16x16x32_bf16(
                        vf, pf[n], o[dt][n], 0, 0, 0);
            }
        }
        __syncthreads();
    }

    #pragma unroll
    for (int n = 0; n < 2; ++n) {
        const float inv = 1.f / lrun[n];
        const int q = q0 + n * 16 + lq;
        u16* op = out + (size_t)(q * Bv + b) * H + h * DH;
        #pragma unroll
        for (int dt = 0; dt < 2; ++dt)
            #pragma unroll
            for (int jj = 0; jj < 2; ++jj) {
                const unsigned pk = cvt_pk_bf16(o[dt][n][jj*2] * inv,
                                                o[dt][n][jj*2+1] * inv);
                *(unsigned*)(op + dt * 16 + lg * 4 + jj * 2) = pk;
            }
    }
}

// ------- merged residual + LayerNorm (bf16 out), 2 rows per wave ----------
// lane>>5 selects row within wave pair; (lane&31)*8 covers 256 cols (16B/lane)
__global__ __launch_bounds__(256) void k_add_ln(
    const u16* __restrict__ x1, const u16* __restrict__ x2,
    const u16* __restrict__ r1, const u16* __restrict__ r2,
    const float* __restrict__ gs1, const float* __restrict__ gs2,
    const float* __restrict__ gb1, const float* __restrict__ gb2,
    u16* __restrict__ y1, u16* __restrict__ y2)
{
    const int wave = threadIdx.x >> 6, lane = threadIdx.x & 63;
    size_t row = (size_t)blockIdx.x * 8 + wave * 2 + (lane >> 5);
    const u16 *x, *r; const float *gs, *gb; u16* y;
    if (row < N1) { x = x1; r = r1; gs = gs1; gb = gb1; y = y1; }
    else { row -= N1; x = x2; r = r2; gs = gs2; gb = gb2; y = y2; }
    const int c = (lane & 31) * 8;
    const ushort8_t xv = *(const ushort8_t*)(x + row * H + c);
    const ushort8_t rv = *(const ushort8_t*)(r + row * H + c);
    float v[8];
    float sum = 0.f, sq = 0.f;
    #pragma unroll
    for (int e = 0; e < 8; ++e) {
        v[e] = bf2f(xv[e]) + bf2f(rv[e]);
        sum += v[e]; sq += v[e] * v[e];
    }
    #pragma unroll
    for (int off = 1; off < 32; off <<= 1) {      // stays within 32-lane half
        sum += __shfl_xor(sum, off);
        sq  += __shfl_xor(sq, off);
    }
    const float mean = sum * (1.f / H);
    const float var  = sq * (1.f / H) - mean * mean;
    const float is   = rsqrtf(var + 1e-5f);
    const float4 s0 = *(const float4*)(gs + c);
    const float4 s1 = *(const float4*)(gs + c + 4);
    const float4 b0 = *(const float4*)(gb + c);
    const float4 b1 = *(const float4*)(gb + c + 4);
    const float gsa[8] = {s0.x,s0.y,s0.z,s0.w,s1.x,s1.y,s1.z,s1.w};
    const float gba[8] = {b0.x,b0.y,b0.z,b0.w,b1.x,b1.y,b1.z,b1.w};
    ushort8_t o;
    #pragma unroll
    for (int e = 0; e < 8; ++e)
        o[e] = f2bf((v[e] - mean) * is * gsa[e] + gba[e]);
    *(ushort8_t*)(y + row * H + c) = o;
}

// ------- merged residual + LayerNorm (f32 out, to d_out), 2 rows/wave -----
__global__ __launch_bounds__(256) void k_add_ln_f32(
    const u16* __restrict__ x1, const u16* __restrict__ x2,
    const u16* __restrict__ r1, const u16* __restrict__ r2,
    const float* __restrict__ gs1, const float* __restrict__ gs2,
    const float* __restrict__ gb1, const float* __restrict__ gb2,
    float* __restrict__ y)
{
    const int wave = threadIdx.x >> 6, lane = threadIdx.x & 63;
    const size_t grow = (size_t)blockIdx.x * 8 + wave * 2 + (lane >> 5);
    const int c = (lane & 31) * 8;
    float* yp = y + grow * H + c;
    size_t row = grow;
    const u16 *x, *r; const float *gs, *gb;
    if (row < N1) { x = x1; r = r1; gs = gs1; gb = gb1; }
    else { row -= N1; x = x2; r = r2; gs = gs2; gb = gb2; }
    const ushort8_t xv = *(const ushort8_t*)(x + row * H + c);
    const ushort8_t rv = *(const ushort8_t*)(r + row * H + c);
    float v[8];
    float sum = 0.f, sq = 0.f;
    #pragma unroll
    for (int e = 0; e < 8; ++e) {
        v[e] = bf2f(xv[e]) + bf2f(rv[e]);
        sum += v[e]; sq += v[e] * v[e];
    }
    #pragma unroll
    for (int off = 1; off < 32; off <<= 1) {
        sum += __shfl_xor(sum, off);
        sq  += __shfl_xor(sq, off);
    }
    const float mean = sum * (1.f / H);
    const float var  = sq * (1.f / H) - mean * mean;
    const float is   = rsqrtf(var + 1e-5f);
    const float4 s0 = *(const float4*)(gs + c);
    const float4 s1 = *(const float4*)(gs + c + 4);
    const float4 b0 = *(const float4*)(gb + c);
    const float4 b1 = *(const float4*)(gb + c + 4);
    float4 o0, o1;
    o0.x = (v[0]-mean)*is*s0.x + b0.x;  o0.y = (v[1]-mean)*is*s0.y + b0.y;
    o0.z = (v[2]-mean)*is*s0.z + b0.z;  o0.w = (v[3]-mean)*is*s0.w + b0.w;
    o1.x = (v[4]-mean)*is*s1.x + b1.x;  o1.y = (v[5]-mean)*is*s1.y + b1.y;
    o1.z = (v[6]-mean)*is*s1.z + b1.z;  o1.w = (v[7]-mean)*is*s1.w + b1.w;
    *(float4*)yp = o0;
    *(float4*)(yp + 4) = o1;
}

// --------------------------------------------------------------------------
extern "C" void kernel_launch(void* const* d_in, const int* in_sizes, int n_in,
                              void* d_out, int out_size, void* d_ws, size_t ws_size,
                              hipStream_t stream)
{
    const int* units = (const int*)d_in[0];
    const int* paths = (const int*)d_in[1];
    const float* emb = (const float*)d_in[4];          // f32 inputs
    const float* const* ep = (const float* const*)(d_in + 5);
    const float* const* od = (const float* const*)(d_in + 17);
    float* out = (float*)d_out;                        // f32 output

    // workspace (~220 MB): separate enc1/enc2 activations + bf16 weights
    u16* bufX1   = (u16*)d_ws;
    u16* bufX2   = bufX1 + (size_t)N1 * H;
    u16* bufBig1 = bufX2 + (size_t)N2 * H;
    u16* bufBig2 = bufBig1 + (size_t)N1 * FFDIM;
    u16* bufO1   = bufBig2 + (size_t)N2 * FFDIM;
    u16* bufO2   = bufO1 + (size_t)N1 * H;
    int* tokb1   = (int*)(bufO2 + (size_t)N2 * H);
    int* tokb2   = tokb1 + N1;
    u16* wbuf    = (u16*)(tokb2 + N2);                 // 2*encstride bf16
    const int wqkv = 2 * 768 * H, wout = 2 * H * H,
              wff1 = 2 * FFDIM * H, wff2 = 2 * H * FFDIM;
    const int encstride = wqkv + wout + wff1 + wff2;   // 1572864
    float* qbias = (float*)(wbuf + 2 * (size_t)encstride);  // 3072 f32 scaled

    // one dispatch converts all 8 weight matrices (Q rows pre-scaled)
    k_f2bf8<<<(2 * encstride) / 1024, 256, 0, stream>>>(
        ep[0], ep[2], ep[6], ep[8], od[0], od[2], od[6], od[8], wbuf);
    // scaled qkv biases (f32)
    k_scaleb<<<12, 256, 0, stream>>>(ep[1], od[1], qbias);

    // merged gather
    k_gather<<<(N1 + N2) / 4, 256, 0, stream>>>(units, paths, emb,
                                                bufX1, bufX2, tokb1, tokb2);

    for (int layer = 0; layer < 2; ++layer) {
        const u16* wb1 = wbuf;
        const u16* wb2 = wbuf + (size_t)encstride;
        const u16* qkvw1 = wb1 + (size_t)layer * 768 * H;
        const u16* qkvw2 = wb2 + (size_t)layer * 768 * H;
        const u16* outw1 = wb1 + wqkv + (size_t)layer * H * H;
        const u16* outw2 = wb2 + wqkv + (size_t)layer * H * H;
        const u16* ff1w1 = wb1 + wqkv + wout + (size_t)layer * FFDIM * H;
        const u16* ff1w2 = wb2 + wqkv + wout + (size_t)layer * FFDIM * H;
        const u16* ff2w1 = wb1 + wqkv + wout + wff1 + (size_t)layer * H * FFDIM;
        const u16* ff2w2 = wb2 + wqkv + wout + wff1 + (size_t)layer * H * FFDIM;
        const float* qkvb1 = qbias + (size_t)layer * 768;
        const float* qkvb2 = qbias + 1536 + (size_t)layer * 768;
        const float* outb1 = ep[3] + (size_t)layer * H;
        const float* outb2 = od[3] + (size_t)layer * H;
        const float* ln1s1 = ep[4] + (size_t)layer * H;
        const float* ln1s2 = od[4] + (size_t)layer * H;
        const float* ln1b1 = ep[5] + (size_t)layer * H;
        const float* ln1b2 = od[5] + (size_t)layer * H;
        const float* ff1b1 = ep[7] + (size_t)layer * FFDIM;
        const float* ff1b2 = od[7] + (size_t)layer * FFDIM;
        const float* ff2b1 = ep[9] + (size_t)layer * H;
        const float* ff2b2 = od[9] + (size_t)layer * H;
        const float* ln2s1 = ep[10] + (size_t)layer * H;
        const float* ln2s2 = od[10] + (size_t)layer * H;
        const float* ln2b1 = ep[11] + (size_t)layer * H;
        const float* ln2b2 = od[11] + (size_t)layer * H;

        // qkv projection (merged; Q pre-scaled via weights/bias)
        k_gemm_mfma<<<(RT1 + RT2) * (768 / 128), 256, 0, stream>>>(
            bufX1, bufX2, qkvw1, qkvw2, qkvb1, qkvb2, bufBig1, bufBig2, H, 768, 0);
        // attention (merged)
        k_attn_mfma<<<B1 * NH + B2 * NH * (L2 / 128), 256, 0, stream>>>(
            bufBig1, bufBig2, tokb1, tokb2, bufO1, bufO2);
        // out-proj (merged)
        k_gemm_mfma<<<(RT1 + RT2) * (H / 128), 256, 0, stream>>>(
            bufO1, bufO2, outw1, outw2, outb1, outb2, bufBig1, bufBig2, H, H, 0);
        // x = LN(x + attnproj) (merged)
        k_add_ln<<<(N1 + N2) / 8, 256, 0, stream>>>(
            bufX1, bufX2, bufBig1, bufBig2, ln1s1, ln1s2, ln1b1, ln1b2, bufX1, bufX2);
        // ff1 + relu (merged)
        k_gemm_mfma<<<(RT1 + RT2) * (FFDIM / 128), 256, 0, stream>>>(
            bufX1, bufX2, ff1w1, ff1w2, ff1b1, ff1b2, bufBig1, bufBig2, H, FFDIM, 1);
        // ff2 (merged)
        k_gemm_mfma<<<(RT1 + RT2) * (H / 128), 256, 0, stream>>>(
            bufBig1, bufBig2, ff2w1, ff2w2, ff2b1, ff2b2, bufO1, bufO2, FFDIM, H, 0);
        // x = LN(x + ff)
        if (layer == 1)
            k_add_ln_f32<<<(N1 + N2) / 8, 256, 0, stream>>>(
                bufX1, bufX2, bufO1, bufO2, ln2s1, ln2s2, ln2b1, ln2b2, out);
        else
            k_add_ln<<<(N1 + N2) / 8, 256, 0, stream>>>(
                bufX1, bufX2, bufO1, bufO2, ln2s1, ln2s2, ln2b1, ln2b2, bufX1, bufX2);
    }
}